// Round 1
// baseline (332.938 us; speedup 1.0000x reference)
//
#include <hip/hip_runtime.h>

#define N_NODES 100000
#define N_EDGES 1600000
#define NB1 98  // ceil(100000/1024) scan blocks

// ---------------- CSR build ----------------

__global__ __launch_bounds__(256) void k_init(int* __restrict__ deg) {
    int i = blockIdx.x * 256 + threadIdx.x;
    if (i < N_NODES) deg[i] = 1;  // self loop
}

__global__ __launch_bounds__(256) void k_degcount(const int* __restrict__ ei, int* __restrict__ deg) {
    int e = blockIdx.x * 256 + threadIdx.x;
    if (e < N_EDGES) atomicAdd(&deg[ei[N_EDGES + e]], 1);
}

__global__ __launch_bounds__(256) void k_scan1(const int* __restrict__ deg, int* __restrict__ rowptr,
                                               int* __restrict__ partials, float* __restrict__ invs) {
    __shared__ int lds[256];
    int t = threadIdx.x;
    int base = blockIdx.x * 1024;
    int v[4];
    int s = 0;
#pragma unroll
    for (int i = 0; i < 4; ++i) {
        int idx = base + t * 4 + i;
        int d = (idx < N_NODES) ? deg[idx] : 0;
        v[i] = d;
        s += d;
        if (idx < N_NODES) invs[idx] = rsqrtf((float)d);
    }
    lds[t] = s;
    __syncthreads();
    for (int off = 1; off < 256; off <<= 1) {
        int xv = (t >= off) ? lds[t - off] : 0;
        __syncthreads();
        lds[t] += xv;
        __syncthreads();
    }
    if (t == 255) partials[blockIdx.x] = lds[255];
    int run = (t > 0) ? lds[t - 1] : 0;
#pragma unroll
    for (int i = 0; i < 4; ++i) {
        int idx = base + t * 4 + i;
        if (idx < N_NODES) rowptr[idx] = run;
        run += v[i];
    }
}

__global__ __launch_bounds__(256) void k_scan2(int* __restrict__ partials) {
    __shared__ int lds[256];
    int t = threadIdx.x;
    lds[t] = (t < NB1) ? partials[t] : 0;
    __syncthreads();
    for (int off = 1; off < 256; off <<= 1) {
        int xv = (t >= off) ? lds[t - off] : 0;
        __syncthreads();
        lds[t] += xv;
        __syncthreads();
    }
    int excl = (t > 0) ? lds[t - 1] : 0;
    if (t < NB1) partials[t] = excl;
}

__global__ __launch_bounds__(256) void k_scan3_fill(int* __restrict__ rowptr, const int* __restrict__ partials,
                                                   int* __restrict__ col, int* __restrict__ cnt) {
    int i = blockIdx.x * 256 + threadIdx.x;
    if (i < N_NODES) {
        int r = rowptr[i] + partials[i >> 10];
        rowptr[i] = r;
        col[r] = i;  // self loop occupies slot 0 of each row
        cnt[i] = 1;
    }
    if (i == 0) rowptr[N_NODES] = N_NODES + N_EDGES;
}

__global__ __launch_bounds__(256) void k_fill(const int* __restrict__ ei, const int* __restrict__ rowptr,
                                              int* __restrict__ cnt, int* __restrict__ col) {
    int e = blockIdx.x * 256 + threadIdx.x;
    if (e < N_EDGES) {
        int s = ei[e];
        int d = ei[N_EDGES + e];
        int pos = rowptr[d] + atomicAdd(&cnt[d], 1);
        col[pos] = s;
    }
}

// ---------------- GEMM1: [100000,128] @ [128,64], epilogue scale by invs[row] ----------------
// block: 256 thr = 8 colgroups(8 cols) x 32 rowgroups(2 rows) -> 64 rows/block
__global__ __launch_bounds__(256) void k_gemm1(const float* __restrict__ X, const float* __restrict__ W,
                                               const float* __restrict__ invs, float* __restrict__ out) {
    __shared__ float xs[64 * 128];   // 32KB, chunk-swizzled
    __shared__ float wsh[128 * 64];  // 32KB
    int t = threadIdx.x;
    int row_base = blockIdx.x * 64;
    {
        const float4* Wv = (const float4*)W;
        float4* d = (float4*)wsh;
#pragma unroll
        for (int i = 0; i < 8; ++i) d[t + i * 256] = Wv[t + i * 256];
    }
    {
        int nvalid = N_NODES - row_base;
        if (nvalid > 64) nvalid = 64;
        int nv4 = nvalid * 32;
        const float4* Xv = (const float4*)(X + (size_t)row_base * 128);
#pragma unroll
        for (int i = 0; i < 8; ++i) {
            int idx = t + i * 256;  // 0..2047
            float4 val = (idx < nv4) ? Xv[idx] : make_float4(0.f, 0.f, 0.f, 0.f);
            int row = idx >> 5, kc = idx & 31;
            int kcs = kc ^ ((row >> 1) & 7);
            *(float4*)&xs[row * 128 + kcs * 4] = val;
        }
    }
    __syncthreads();
    int cg = t & 7, rg = t >> 3;
    int c0 = cg * 8;
    int r0 = rg * 2;
    int sw = rg & 7;
    float acc[2][8];
#pragma unroll
    for (int i = 0; i < 2; ++i)
#pragma unroll
        for (int j = 0; j < 8; ++j) acc[i][j] = 0.f;

#pragma unroll 4
    for (int kc = 0; kc < 32; ++kc) {
        int kcs = kc ^ sw;
        float4 xa = *(const float4*)&xs[r0 * 128 + kcs * 4];
        float4 xb = *(const float4*)&xs[(r0 + 1) * 128 + kcs * 4];
        int k = kc * 4;
#pragma unroll
        for (int kk = 0; kk < 4; ++kk) {
            float4 wlo = *(const float4*)&wsh[(k + kk) * 64 + c0];
            float4 whi = *(const float4*)&wsh[(k + kk) * 64 + c0 + 4];
            float xav = (&xa.x)[kk];
            float xbv = (&xb.x)[kk];
            acc[0][0] += xav * wlo.x; acc[0][1] += xav * wlo.y;
            acc[0][2] += xav * wlo.z; acc[0][3] += xav * wlo.w;
            acc[0][4] += xav * whi.x; acc[0][5] += xav * whi.y;
            acc[0][6] += xav * whi.z; acc[0][7] += xav * whi.w;
            acc[1][0] += xbv * wlo.x; acc[1][1] += xbv * wlo.y;
            acc[1][2] += xbv * wlo.z; acc[1][3] += xbv * wlo.w;
            acc[1][4] += xbv * whi.x; acc[1][5] += xbv * whi.y;
            acc[1][6] += xbv * whi.z; acc[1][7] += xbv * whi.w;
        }
    }
#pragma unroll
    for (int r = 0; r < 2; ++r) {
        int row = row_base + r0 + r;
        if (row < N_NODES) {
            float iv = invs[row];
            float4 o0 = make_float4(acc[r][0] * iv, acc[r][1] * iv, acc[r][2] * iv, acc[r][3] * iv);
            float4 o1 = make_float4(acc[r][4] * iv, acc[r][5] * iv, acc[r][6] * iv, acc[r][7] * iv);
            *(float4*)&out[(size_t)row * 64 + c0] = o0;
            *(float4*)&out[(size_t)row * 64 + c0 + 4] = o1;
        }
    }
}

// ---------------- GEMM2: [100000,64] @ [64,32], epilogue scale by invs[row] ----------------
// block: 256 thr = 4 colgroups(8 cols) x 64 rowgroups(2 rows) -> 128 rows/block
__global__ __launch_bounds__(256) void k_gemm2(const float* __restrict__ X, const float* __restrict__ W,
                                               const float* __restrict__ invs, float* __restrict__ out) {
    __shared__ float xs[128 * 64];  // 32KB, chunk-swizzled
    __shared__ float wsh[64 * 32];  // 8KB
    int t = threadIdx.x;
    int row_base = blockIdx.x * 128;
    {
        const float4* Wv = (const float4*)W;
        float4* d = (float4*)wsh;
#pragma unroll
        for (int i = 0; i < 2; ++i) d[t + i * 256] = Wv[t + i * 256];
    }
    {
        int nvalid = N_NODES - row_base;
        if (nvalid > 128) nvalid = 128;
        int nv4 = nvalid * 16;
        const float4* Xv = (const float4*)(X + (size_t)row_base * 64);
#pragma unroll
        for (int i = 0; i < 8; ++i) {
            int idx = t + i * 256;  // 0..2047
            float4 val = (idx < nv4) ? Xv[idx] : make_float4(0.f, 0.f, 0.f, 0.f);
            int row = idx >> 4, kc = idx & 15;
            int kcs = kc ^ ((row >> 1) & 7);
            *(float4*)&xs[row * 64 + kcs * 4] = val;
        }
    }
    __syncthreads();
    int cg = t & 3, rg = t >> 2;
    int c0 = cg * 8;
    int r0 = rg * 2;
    int sw = rg & 7;
    float acc[2][8];
#pragma unroll
    for (int i = 0; i < 2; ++i)
#pragma unroll
        for (int j = 0; j < 8; ++j) acc[i][j] = 0.f;

#pragma unroll 4
    for (int kc = 0; kc < 16; ++kc) {
        int kcs = kc ^ sw;
        float4 xa = *(const float4*)&xs[r0 * 64 + kcs * 4];
        float4 xb = *(const float4*)&xs[(r0 + 1) * 64 + kcs * 4];
        int k = kc * 4;
#pragma unroll
        for (int kk = 0; kk < 4; ++kk) {
            float4 wlo = *(const float4*)&wsh[(k + kk) * 32 + c0];
            float4 whi = *(const float4*)&wsh[(k + kk) * 32 + c0 + 4];
            float xav = (&xa.x)[kk];
            float xbv = (&xb.x)[kk];
            acc[0][0] += xav * wlo.x; acc[0][1] += xav * wlo.y;
            acc[0][2] += xav * wlo.z; acc[0][3] += xav * wlo.w;
            acc[0][4] += xav * whi.x; acc[0][5] += xav * whi.y;
            acc[0][6] += xav * whi.z; acc[0][7] += xav * whi.w;
            acc[1][0] += xbv * wlo.x; acc[1][1] += xbv * wlo.y;
            acc[1][2] += xbv * wlo.z; acc[1][3] += xbv * wlo.w;
            acc[1][4] += xbv * whi.x; acc[1][5] += xbv * whi.y;
            acc[1][6] += xbv * whi.z; acc[1][7] += xbv * whi.w;
        }
    }
#pragma unroll
    for (int r = 0; r < 2; ++r) {
        int row = row_base + r0 + r;
        if (row < N_NODES) {
            float iv = invs[row];
            float4 o0 = make_float4(acc[r][0] * iv, acc[r][1] * iv, acc[r][2] * iv, acc[r][3] * iv);
            float4 o1 = make_float4(acc[r][4] * iv, acc[r][5] * iv, acc[r][6] * iv, acc[r][7] * iv);
            *(float4*)&out[(size_t)row * 32 + c0] = o0;
            *(float4*)&out[(size_t)row * 32 + c0 + 4] = o1;
        }
    }
}

// ---------------- SpMM: agg[i] = invs[i] * sum_j hs[col[j]] + bias, optional relu ----------------
// layer1: C=64, one 64-lane wave per node
__global__ __launch_bounds__(256) void k_spmm1(const float* __restrict__ hs, const int* __restrict__ rowptr,
                                               const int* __restrict__ col, const float* __restrict__ invs,
                                               const float* __restrict__ b, float* __restrict__ out) {
    int t = threadIdx.x;
    int node = blockIdx.x * 4 + (t >> 6);
    int c = t & 63;
    int ps = rowptr[node], pe = rowptr[node + 1];
    float acc = 0.f;
    int p = ps;
    for (; p + 4 <= pe; p += 4) {
        int j0 = col[p], j1 = col[p + 1], j2 = col[p + 2], j3 = col[p + 3];
        float a0 = hs[(size_t)j0 * 64 + c];
        float a1 = hs[(size_t)j1 * 64 + c];
        float a2 = hs[(size_t)j2 * 64 + c];
        float a3 = hs[(size_t)j3 * 64 + c];
        acc += a0; acc += a1; acc += a2; acc += a3;
    }
    for (; p < pe; ++p) acc += hs[(size_t)col[p] * 64 + c];
    float v = acc * invs[node] + b[c];
    out[(size_t)node * 64 + c] = fmaxf(v, 0.f);
}

// layer2: C=32, 32 lanes per node
__global__ __launch_bounds__(256) void k_spmm2(const float* __restrict__ hs, const int* __restrict__ rowptr,
                                               const int* __restrict__ col, const float* __restrict__ invs,
                                               const float* __restrict__ b, float* __restrict__ out) {
    int t = threadIdx.x;
    int node = blockIdx.x * 8 + (t >> 5);
    int c = t & 31;
    int ps = rowptr[node], pe = rowptr[node + 1];
    float acc = 0.f;
    int p = ps;
    for (; p + 4 <= pe; p += 4) {
        int j0 = col[p], j1 = col[p + 1], j2 = col[p + 2], j3 = col[p + 3];
        float a0 = hs[(size_t)j0 * 32 + c];
        float a1 = hs[(size_t)j1 * 32 + c];
        float a2 = hs[(size_t)j2 * 32 + c];
        float a3 = hs[(size_t)j3 * 32 + c];
        acc += a0; acc += a1; acc += a2; acc += a3;
    }
    for (; p < pe; ++p) acc += hs[(size_t)col[p] * 32 + c];
    out[(size_t)node * 32 + c] = acc * invs[node] + b[c];
}

extern "C" void kernel_launch(void* const* d_in, const int* in_sizes, int n_in,
                              void* d_out, int out_size, void* d_ws, size_t ws_size,
                              hipStream_t stream) {
    const float* x  = (const float*)d_in[0];
    const int*   ei = (const int*)d_in[1];
    const float* W1 = (const float*)d_in[2];
    const float* b1 = (const float*)d_in[3];
    const float* W2 = (const float*)d_in[4];
    const float* b2 = (const float*)d_in[5];
    float* out = (float*)d_out;

    char* ws = (char*)d_ws;
    size_t off = 0;
    auto alloc = [&](size_t bytes) -> void* {
        void* p = ws + off;
        off = (off + bytes + 255) & ~(size_t)255;
        return p;
    };
    int*   deg      = (int*)alloc((size_t)N_NODES * 4);
    int*   cnt      = (int*)alloc((size_t)N_NODES * 4);
    int*   rowptr   = (int*)alloc((size_t)(N_NODES + 1) * 4);
    float* invs     = (float*)alloc((size_t)N_NODES * 4);
    int*   partials = (int*)alloc(256 * 4);
    int*   col      = (int*)alloc((size_t)(N_NODES + N_EDGES) * 4);
    float* hs1      = (float*)alloc((size_t)N_NODES * 64 * 4);
    float* h2in     = (float*)alloc((size_t)N_NODES * 64 * 4);
    float* hs2      = hs1;  // hs1 dead after spmm1; reuse for layer-2 transformed feats

    k_init<<<(N_NODES + 255) / 256, 256, 0, stream>>>(deg);
    k_degcount<<<(N_EDGES + 255) / 256, 256, 0, stream>>>(ei, deg);
    k_scan1<<<NB1, 256, 0, stream>>>(deg, rowptr, partials, invs);
    k_scan2<<<1, 256, 0, stream>>>(partials);
    k_scan3_fill<<<(N_NODES + 255) / 256, 256, 0, stream>>>(rowptr, partials, col, cnt);
    k_fill<<<(N_EDGES + 255) / 256, 256, 0, stream>>>(ei, rowptr, cnt, col);
    k_gemm1<<<(N_NODES + 63) / 64, 256, 0, stream>>>(x, W1, invs, hs1);
    k_spmm1<<<N_NODES / 4, 256, 0, stream>>>(hs1, rowptr, col, invs, b1, h2in);
    k_gemm2<<<(N_NODES + 127) / 128, 256, 0, stream>>>(h2in, W2, invs, hs2);
    k_spmm2<<<N_NODES / 8, 256, 0, stream>>>(hs2, rowptr, col, invs, b2, out);
}